// Round 4
// baseline (92.391 us; speedup 1.0000x reference)
//
#include <hip/hip_runtime.h>

// Problem constants (match reference setup_inputs)
#define BATCH 2048
#define NPTS  8192

// convert_to_radar_frame constants: cart_min_range = (640/2 - 0.5) * 0.2592
#define RES 0.2592f
#define CMR 82.8144f

__device__ __forceinline__ float wave_reduce_add(float v) {
    #pragma unroll
    for (int off = 32; off > 0; off >>= 1) v += __shfl_down(v, off, 64);
    return v;
}

__global__ __launch_bounds__(256, 4) void svd_align_kernel(
    const float* __restrict__ src, const float* __restrict__ tgt,
    const float* __restrict__ wts, const int* __restrict__ cvt_flag,
    float* __restrict__ out)
{
    const int b   = blockIdx.x;
    const int tid = threadIdx.x;
    const int convert = *cvt_flag;  // uniform

    // Branch-free conversion coefficients (identity when convert==0):
    //   x' = fmaf(Ax, (convert ? y : x), Bx);  y' = fmaf(Ay, (convert ? x : y), By)
    const float Ax = convert ? -RES : 1.0f;
    const float Bx = convert ?  CMR : 0.0f;
    const float Ay = convert ?  RES : 1.0f;
    const float By = convert ? -CMR : 0.0f;

    const float4* s4  = (const float4*)(src + (size_t)b * NPTS * 2);
    const float4* t4  = (const float4*)(tgt + (size_t)b * NPTS * 2);
    const float2* w2p = (const float2*)(wts + (size_t)b * NPTS);

    // 9 accumulators
    float aW = 0.f, aSx = 0.f, aSy = 0.f, aTx = 0.f, aTy = 0.f;
    float aXX = 0.f, aXY = 0.f, aYX = 0.f, aYY = 0.f;

    // Three NAMED buffer sets (no arrays, no rotation copies -> no spill bait).
    float4 sb0, tb0, sb1, tb1, sb2, tb2;
    float2 wb0, wb1, wb2;

#define LOADC(S, idx) do {                       \
        const int k_ = (idx) * 256 + tid;        \
        sb##S = s4[k_];                          \
        tb##S = t4[k_];                          \
        wb##S = w2p[k_];                         \
    } while (0)

#define PROC(S) do {                                                   \
        float sx0 = fmaf(Ax, convert ? sb##S.y : sb##S.x, Bx);         \
        float sy0 = fmaf(Ay, convert ? sb##S.x : sb##S.y, By);         \
        float sx1 = fmaf(Ax, convert ? sb##S.w : sb##S.z, Bx);         \
        float sy1 = fmaf(Ay, convert ? sb##S.z : sb##S.w, By);         \
        float tx0 = fmaf(Ax, convert ? tb##S.y : tb##S.x, Bx);         \
        float ty0 = fmaf(Ay, convert ? tb##S.x : tb##S.y, By);         \
        float tx1 = fmaf(Ax, convert ? tb##S.w : tb##S.z, Bx);         \
        float ty1 = fmaf(Ay, convert ? tb##S.z : tb##S.w, By);         \
        float wv  = wb##S.x;                                           \
        float wtx = wv * tx0, wty = wv * ty0;                          \
        aW  += wv;                                                     \
        aSx = fmaf(wv, sx0, aSx);  aSy = fmaf(wv, sy0, aSy);           \
        aTx += wtx;                aTy += wty;                         \
        aXX = fmaf(wtx, sx0, aXX); aXY = fmaf(wtx, sy0, aXY);          \
        aYX = fmaf(wty, sx0, aYX); aYY = fmaf(wty, sy0, aYY);          \
        wv  = wb##S.y;                                                 \
        wtx = wv * tx1; wty = wv * ty1;                                \
        aW  += wv;                                                     \
        aSx = fmaf(wv, sx1, aSx);  aSy = fmaf(wv, sy1, aSy);           \
        aTx += wtx;                aTy += wty;                         \
        aXX = fmaf(wtx, sx1, aXX); aXY = fmaf(wtx, sy1, aXY);          \
        aYX = fmaf(wty, sx1, aYX); aYY = fmaf(wty, sy1, aYY);          \
    } while (0)

    // Distance-2 software pipeline, fully peeled & static.
    // Step i: issue load of chunk i+2 into slot (i+2)%3, then process slot i%3.
    LOADC(0, 0);
    LOADC(1, 1);

    LOADC(2, 2);   PROC(0);   // i=0
    LOADC(0, 3);   PROC(1);   // i=1
    LOADC(1, 4);   PROC(2);   // i=2
    LOADC(2, 5);   PROC(0);   // i=3
    LOADC(0, 6);   PROC(1);   // i=4
    LOADC(1, 7);   PROC(2);   // i=5
    LOADC(2, 8);   PROC(0);   // i=6
    LOADC(0, 9);   PROC(1);   // i=7
    LOADC(1, 10);  PROC(2);   // i=8
    LOADC(2, 11);  PROC(0);   // i=9
    LOADC(0, 12);  PROC(1);   // i=10
    LOADC(1, 13);  PROC(2);   // i=11
    LOADC(2, 14);  PROC(0);   // i=12
    LOADC(0, 15);  PROC(1);   // i=13
    PROC(2);                  // i=14
    PROC(0);                  // i=15

#undef LOADC
#undef PROC

    // wave64 reduce each accumulator
    aW  = wave_reduce_add(aW);
    aSx = wave_reduce_add(aSx);  aSy = wave_reduce_add(aSy);
    aTx = wave_reduce_add(aTx);  aTy = wave_reduce_add(aTy);
    aXX = wave_reduce_add(aXX);  aXY = wave_reduce_add(aXY);
    aYX = wave_reduce_add(aYX);  aYY = wave_reduce_add(aYY);

    __shared__ float red[4][9];
    const int wave = tid >> 6;
    if ((tid & 63) == 0) {
        red[wave][0] = aW;
        red[wave][1] = aSx; red[wave][2] = aSy;
        red[wave][3] = aTx; red[wave][4] = aTy;
        red[wave][5] = aXX; red[wave][6] = aXY;
        red[wave][7] = aYX; red[wave][8] = aYY;
    }
    __syncthreads();

    if (tid == 0) {
        double Sw = 0, Ssx = 0, Ssy = 0, Stx = 0, Sty = 0;
        double Sxx = 0, Sxy = 0, Syx = 0, Syy = 0;
        #pragma unroll
        for (int i = 0; i < 4; ++i) {
            Sw  += red[i][0];
            Ssx += red[i][1]; Ssy += red[i][2];
            Stx += red[i][3]; Sty += red[i][4];
            Sxx += red[i][5]; Sxy += red[i][6];
            Syx += red[i][7]; Syy += red[i][8];
        }

        const double wd  = Sw + 1e-4;
        const double scx = Ssx / wd, scy = Ssy / wd;
        const double tcx = Stx / wd, tcy = Sty / wd;

        const double W00 = (Sxx - tcx * Ssx - scx * Stx + tcx * scx * Sw) / wd;
        const double W01 = (Sxy - tcx * Ssy - scy * Stx + tcx * scy * Sw) / wd;
        const double W10 = (Syx - tcy * Ssx - scx * Sty + tcy * scx * Sw) / wd;
        const double W11 = (Syy - tcy * Ssy - scy * Sty + tcy * scy * Sw) / wd;

        const double det = W00 * W11 - W01 * W10;

        // 2x2 orthogonal polar factor of W (== U2 @ V2^T), and
        // R[2][2] = sign(det) from Kabsch diag(1,1,detU*detV).
        double R00, R01, R10, R11, dsign;
        if (det >= 0.0) {
            const double p = W00 + W11;
            const double q = W10 - W01;
            double r = sqrt(p * p + q * q);
            if (r > 0.0) {
                R00 = p / r;  R01 = -q / r;
                R10 = q / r;  R11 = p / r;
            } else {
                R00 = 1.0; R01 = 0.0; R10 = 0.0; R11 = 1.0;
            }
            dsign = 1.0;
        } else {
            const double p = W00 - W11;
            const double q = W01 + W10;
            const double r = sqrt(p * p + q * q);  // > 0 when det < 0
            R00 = p / r;   R01 = q / r;
            R10 = q / r;   R11 = -p / r;
            dsign = -1.0;
        }

        // t_tgt_src_insrc = src_centroid - R^T @ tgt_centroid (z == 0)
        const double tt0 = scx - (R00 * tcx + R10 * tcy);
        const double tt1 = scy - (R01 * tcx + R11 * tcy);
        // t_src_tgt_intgt = -R @ t_tgt_src_insrc
        const double o0 = -(R00 * tt0 + R01 * tt1);
        const double o1 = -(R10 * tt0 + R11 * tt1);

        // Output 0: R^T, row-major [3][3]
        float* oR = out + (size_t)b * 9;
        oR[0] = (float)R00; oR[1] = (float)R10; oR[2] = 0.f;
        oR[3] = (float)R01; oR[4] = (float)R11; oR[5] = 0.f;
        oR[6] = 0.f;        oR[7] = 0.f;        oR[8] = (float)dsign;

        // Output 1: translation [3][1]
        float* oT = out + (size_t)BATCH * 9 + (size_t)b * 3;
        oT[0] = (float)o0; oT[1] = (float)o1; oT[2] = 0.f;
    }
}

extern "C" void kernel_launch(void* const* d_in, const int* in_sizes, int n_in,
                              void* d_out, int out_size, void* d_ws, size_t ws_size,
                              hipStream_t stream) {
    const float* src = (const float*)d_in[0];
    const float* tgt = (const float*)d_in[1];
    const float* wts = (const float*)d_in[2];
    const int*   cvt = (const int*)d_in[3];
    float* out = (float*)d_out;

    svd_align_kernel<<<BATCH, 256, 0, stream>>>(src, tgt, wts, cvt, out);
}

// Round 5
// 65.908 us; speedup vs baseline: 1.4018x; 1.4018x over previous
//
#include <hip/hip_runtime.h>

// Problem constants (match reference setup_inputs)
#define BATCH 2048
#define NPTS  8192

// LDS geometry (floats). Per wave, per buffer = 640 floats (2560 B):
//   [0..255]   s coords (128 pts x 2 floats)
//   [256..511] t coords
//   [512..639] weights (128 floats)
// 3 buffers per wave (depth-2 prefetch), 4 waves per block.
#define BUF_F   640
#define WAVE_F  (3 * BUF_F)
#define LDS_F   (4 * WAVE_F)

__device__ __forceinline__ float wave_reduce_add(float v) {
    #pragma unroll
    for (int off = 32; off > 0; off >>= 1) v += __shfl_down(v, off, 64);
    return v;
}

// Async global->LDS, zero VGPR cost for the payload.
// LDS dest is wave-uniform base + lane*size; global src is per-lane.
__device__ __forceinline__ void gld16(const float* g, float* l) {
    __builtin_amdgcn_global_load_lds(
        (const __attribute__((address_space(1))) void*)g,
        (__attribute__((address_space(3))) void*)l, 16, 0, 0);
}
__device__ __forceinline__ void gld4(const float* g, float* l) {
    __builtin_amdgcn_global_load_lds(
        (const __attribute__((address_space(1))) void*)g,
        (__attribute__((address_space(3))) void*)l, 4, 0, 0);
}

__global__ __launch_bounds__(256) void svd_align_kernel(
    const float* __restrict__ src, const float* __restrict__ tgt,
    const float* __restrict__ wts, const int* __restrict__ cvt_flag,
    float* __restrict__ out)
{
    const int b   = blockIdx.x;
    const int tid = threadIdx.x;
    const int wv  = tid >> 6;    // wave id (uniform within wave)
    const int ln  = tid & 63;    // lane id

    __shared__ __align__(16) float lds[LDS_F];
    __shared__ float red[4][9];

    // Each wave owns NPTS/4 = 2048 points: 16 chunks of 128 points.
    const float* srcW = src + (size_t)b * (NPTS * 2) + wv * 4096;
    const float* tgtW = tgt + (size_t)b * (NPTS * 2) + wv * 4096;
    const float* wtsW = wts + (size_t)b * NPTS + wv * 2048;
    float* myLds = &lds[wv * WAVE_F];

    // Issue one chunk (4 uniform VMEM instructions per lane -> vmcnt +4/wave)
    auto ISSUE = [&](int c) {
        float* sb = myLds + (c % 3) * BUF_F;        // wave-uniform LDS base
        gld16(srcW + c * 256 + ln * 4, sb);         // s: lane l -> pts 2l,2l+1
        gld16(tgtW + c * 256 + ln * 4, sb + 256);
        gld4 (wtsW + c * 128 + ln,      sb + 512);  // w[0..63]   -> idx 512+l
        gld4 (wtsW + c * 128 + 64 + ln, sb + 576);  // w[64..127] -> idx 576+l
    };

    // Prologue: 3 chunks in flight (12 VMEM / wave outstanding).
    ISSUE(0); ISSUE(1); ISSUE(2);

    // 9 raw-coordinate accumulators (conversion applied algebraically in epilogue)
    float aW = 0.f, aSx = 0.f, aSy = 0.f, aTx = 0.f, aTy = 0.f;
    float aXX = 0.f, aXY = 0.f, aYX = 0.f, aYY = 0.f;

    #pragma unroll
    for (int c = 0; c < 16; ++c) {
        // Counted wait: leave the 2 younger chunks (8 loads) in flight.
        if (c <= 13)      asm volatile("s_waitcnt vmcnt(8)" ::: "memory");
        else if (c == 14) asm volatile("s_waitcnt vmcnt(4)" ::: "memory");
        else              asm volatile("s_waitcnt vmcnt(0)" ::: "memory");
        __builtin_amdgcn_sched_barrier(0);

        const float* sb = myLds + (c % 3) * BUF_F;
        const float4 s  = *(const float4*)(sb + (ln << 2));
        const float4 t  = *(const float4*)(sb + 256 + (ln << 2));
        const float2 w2 = *(const float2*)(sb + 512 + (ln << 1));

        // Drain DS reads before this buffer is re-targeted by new loads.
        asm volatile("s_waitcnt lgkmcnt(0)" ::: "memory");
        __builtin_amdgcn_sched_barrier(0);

        if (c + 3 < 16) ISSUE(c + 3);   // refill the buffer just consumed

        // point 0
        {
            const float wgt = w2.x;
            const float wtx = wgt * t.x, wty = wgt * t.y;
            aW  += wgt;
            aSx = fmaf(wgt, s.x, aSx);  aSy = fmaf(wgt, s.y, aSy);
            aTx += wtx;                 aTy += wty;
            aXX = fmaf(wtx, s.x, aXX);  aXY = fmaf(wtx, s.y, aXY);
            aYX = fmaf(wty, s.x, aYX);  aYY = fmaf(wty, s.y, aYY);
        }
        // point 1
        {
            const float wgt = w2.y;
            const float wtx = wgt * t.z, wty = wgt * t.w;
            aW  += wgt;
            aSx = fmaf(wgt, s.z, aSx);  aSy = fmaf(wgt, s.w, aSy);
            aTx += wtx;                 aTy += wty;
            aXX = fmaf(wtx, s.z, aXX);  aXY = fmaf(wtx, s.w, aXY);
            aYX = fmaf(wty, s.z, aYX);  aYY = fmaf(wty, s.w, aYY);
        }
    }

    // wave64 reduce each accumulator
    aW  = wave_reduce_add(aW);
    aSx = wave_reduce_add(aSx);  aSy = wave_reduce_add(aSy);
    aTx = wave_reduce_add(aTx);  aTy = wave_reduce_add(aTy);
    aXX = wave_reduce_add(aXX);  aXY = wave_reduce_add(aXY);
    aYX = wave_reduce_add(aYX);  aYY = wave_reduce_add(aYY);

    if (ln == 0) {
        red[wv][0] = aW;
        red[wv][1] = aSx; red[wv][2] = aSy;
        red[wv][3] = aTx; red[wv][4] = aTy;
        red[wv][5] = aXX; red[wv][6] = aXY;
        red[wv][7] = aYX; red[wv][8] = aYY;
    }
    __syncthreads();

    if (tid == 0) {
        double Sw = 0, Ssx = 0, Ssy = 0, Stx = 0, Sty = 0;
        double Sxx = 0, Sxy = 0, Syx = 0, Syy = 0;
        #pragma unroll
        for (int i = 0; i < 4; ++i) {
            Sw  += red[i][0];
            Ssx += red[i][1]; Ssy += red[i][2];
            Stx += red[i][3]; Sty += red[i][4];
            Sxx += red[i][5]; Sxy += red[i][6];
            Syx += red[i][7]; Syy += red[i][8];
        }

        // Apply the affine pixel->radar conversion to the raw sums (exact):
        //   mx = -r*y + cc ; my = r*x - cc
        if (*cvt_flag) {
            const double r  = 0.2592;
            const double cc = (640.0 / 2 - 0.5) * 0.2592;
            const double nSsx = -r * Ssy + cc * Sw;
            const double nSsy =  r * Ssx - cc * Sw;
            const double nStx = -r * Sty + cc * Sw;
            const double nSty =  r * Stx - cc * Sw;
            const double nSxx =  r * r * Syy - r * cc * (Sty + Ssy) + cc * cc * Sw;
            const double nSxy = -r * r * Syx + r * cc * (Sty + Ssx) - cc * cc * Sw;
            const double nSyx = -r * r * Sxy + r * cc * (Stx + Ssy) - cc * cc * Sw;
            const double nSyy =  r * r * Sxx - r * cc * (Stx + Ssx) + cc * cc * Sw;
            Ssx = nSsx; Ssy = nSsy; Stx = nStx; Sty = nSty;
            Sxx = nSxx; Sxy = nSxy; Syx = nSyx; Syy = nSyy;
        }

        const double wd  = Sw + 1e-4;
        const double scx = Ssx / wd, scy = Ssy / wd;
        const double tcx = Stx / wd, tcy = Sty / wd;

        const double W00 = (Sxx - tcx * Ssx - scx * Stx + tcx * scx * Sw) / wd;
        const double W01 = (Sxy - tcx * Ssy - scy * Stx + tcx * scy * Sw) / wd;
        const double W10 = (Syx - tcy * Ssx - scx * Sty + tcy * scx * Sw) / wd;
        const double W11 = (Syy - tcy * Ssy - scy * Sty + tcy * scy * Sw) / wd;

        const double det = W00 * W11 - W01 * W10;

        // 2x2 orthogonal polar factor of W (== U2 @ V2^T), and
        // R[2][2] = sign(det) from Kabsch diag(1,1,detU*detV).
        double R00, R01, R10, R11, dsign;
        if (det >= 0.0) {
            const double p = W00 + W11;
            const double q = W10 - W01;
            double r2 = sqrt(p * p + q * q);
            if (r2 > 0.0) {
                R00 = p / r2;  R01 = -q / r2;
                R10 = q / r2;  R11 = p / r2;
            } else {
                R00 = 1.0; R01 = 0.0; R10 = 0.0; R11 = 1.0;
            }
            dsign = 1.0;
        } else {
            const double p = W00 - W11;
            const double q = W01 + W10;
            const double r2 = sqrt(p * p + q * q);  // > 0 when det < 0
            R00 = p / r2;   R01 = q / r2;
            R10 = q / r2;   R11 = -p / r2;
            dsign = -1.0;
        }

        // t_tgt_src_insrc = src_centroid - R^T @ tgt_centroid (z == 0)
        const double tt0 = scx - (R00 * tcx + R10 * tcy);
        const double tt1 = scy - (R01 * tcx + R11 * tcy);
        // t_src_tgt_intgt = -R @ t_tgt_src_insrc
        const double o0 = -(R00 * tt0 + R01 * tt1);
        const double o1 = -(R10 * tt0 + R11 * tt1);

        // Output 0: R^T, row-major [3][3]
        float* oR = out + (size_t)b * 9;
        oR[0] = (float)R00; oR[1] = (float)R10; oR[2] = 0.f;
        oR[3] = (float)R01; oR[4] = (float)R11; oR[5] = 0.f;
        oR[6] = 0.f;        oR[7] = 0.f;        oR[8] = (float)dsign;

        // Output 1: translation [3][1]
        float* oT = out + (size_t)BATCH * 9 + (size_t)b * 3;
        oT[0] = (float)o0; oT[1] = (float)o1; oT[2] = 0.f;
    }
}

extern "C" void kernel_launch(void* const* d_in, const int* in_sizes, int n_in,
                              void* d_out, int out_size, void* d_ws, size_t ws_size,
                              hipStream_t stream) {
    const float* src = (const float*)d_in[0];
    const float* tgt = (const float*)d_in[1];
    const float* wts = (const float*)d_in[2];
    const int*   cvt = (const int*)d_in[3];
    float* out = (float*)d_out;

    svd_align_kernel<<<BATCH, 256, 0, stream>>>(src, tgt, wts, cvt, out);
}

// Round 6
// 58.711 us; speedup vs baseline: 1.5736x; 1.1226x over previous
//
#include <hip/hip_runtime.h>

// Problem constants (match reference setup_inputs)
#define BATCH 2048
#define NPTS  8192

__device__ __forceinline__ float wave_reduce_add(float v) {
    #pragma unroll
    for (int off = 32; off > 0; off >>= 1) v += __shfl_down(v, off, 64);
    return v;
}

__global__ __launch_bounds__(256, 4) void svd_align_kernel(
    const float* __restrict__ src, const float* __restrict__ tgt,
    const float* __restrict__ wts, const int* __restrict__ cvt_flag,
    float* __restrict__ out)
{
    const int b   = blockIdx.x;
    const int tid = threadIdx.x;

    const float4* s4 = (const float4*)(src + (size_t)b * NPTS * 2);
    const float4* t4 = (const float4*)(tgt + (size_t)b * NPTS * 2);
    const float4* w4 = (const float4*)(wts + (size_t)b * NPTS);

    // 9 raw-coordinate accumulators (pixel->radar conversion applied
    // algebraically to the sums in the fp64 epilogue — exact, hot loop is
    // pure load+FMA).
    float aW = 0.f, aSx = 0.f, aSy = 0.f, aTx = 0.f, aTy = 0.f;
    float aXX = 0.f, aXY = 0.f, aYX = 0.f, aYY = 0.f;

#define ACCPT(wgt, sx, sy, tx, ty) do {                                \
        const float wtx = (wgt) * (tx), wty = (wgt) * (ty);            \
        aW  += (wgt);                                                  \
        aSx = fmaf((wgt), (sx), aSx);  aSy = fmaf((wgt), (sy), aSy);   \
        aTx += wtx;                    aTy += wty;                     \
        aXX = fmaf(wtx, (sx), aXX);    aXY = fmaf(wtx, (sy), aXY);     \
        aYX = fmaf(wty, (sx), aYX);    aYY = fmaf(wty, (sy), aYY);     \
    } while (0)

    // 4 points per thread per iteration: all VMEM are 16B/lane.
    // 8192 pts / (256 thr * 4 pts) = 8 iterations.
    #pragma unroll 2
    for (int i = 0; i < 8; ++i) {
        const int q = i * 512 + (tid << 1);   // float4 idx into s/t streams
        const float4 sA = s4[q];
        const float4 sB = s4[q + 1];
        const float4 tA = t4[q];
        const float4 tB = t4[q + 1];
        const float4 w  = w4[i * 256 + tid];  // 4 weights, coalesced

        ACCPT(w.x, sA.x, sA.y, tA.x, tA.y);
        ACCPT(w.y, sA.z, sA.w, tA.z, tA.w);
        ACCPT(w.z, sB.x, sB.y, tB.x, tB.y);
        ACCPT(w.w, sB.z, sB.w, tB.z, tB.w);
    }
#undef ACCPT

    // wave64 reduce each accumulator
    aW  = wave_reduce_add(aW);
    aSx = wave_reduce_add(aSx);  aSy = wave_reduce_add(aSy);
    aTx = wave_reduce_add(aTx);  aTy = wave_reduce_add(aTy);
    aXX = wave_reduce_add(aXX);  aXY = wave_reduce_add(aXY);
    aYX = wave_reduce_add(aYX);  aYY = wave_reduce_add(aYY);

    __shared__ float red[4][9];
    const int wave = tid >> 6;
    if ((tid & 63) == 0) {
        red[wave][0] = aW;
        red[wave][1] = aSx; red[wave][2] = aSy;
        red[wave][3] = aTx; red[wave][4] = aTy;
        red[wave][5] = aXX; red[wave][6] = aXY;
        red[wave][7] = aYX; red[wave][8] = aYY;
    }
    __syncthreads();

    if (tid == 0) {
        double Sw = 0, Ssx = 0, Ssy = 0, Stx = 0, Sty = 0;
        double Sxx = 0, Sxy = 0, Syx = 0, Syy = 0;
        #pragma unroll
        for (int i = 0; i < 4; ++i) {
            Sw  += red[i][0];
            Ssx += red[i][1]; Ssy += red[i][2];
            Stx += red[i][3]; Sty += red[i][4];
            Sxx += red[i][5]; Sxy += red[i][6];
            Syx += red[i][7]; Syy += red[i][8];
        }

        // Exact algebraic application of the affine pixel->radar transform
        // to the raw sums:  mx = -r*y + cc ; my = r*x - cc
        if (*cvt_flag) {
            const double r  = 0.2592;
            const double cc = (640.0 / 2 - 0.5) * 0.2592;
            const double nSsx = -r * Ssy + cc * Sw;
            const double nSsy =  r * Ssx - cc * Sw;
            const double nStx = -r * Sty + cc * Sw;
            const double nSty =  r * Stx - cc * Sw;
            const double nSxx =  r * r * Syy - r * cc * (Sty + Ssy) + cc * cc * Sw;
            const double nSxy = -r * r * Syx + r * cc * (Sty + Ssx) - cc * cc * Sw;
            const double nSyx = -r * r * Sxy + r * cc * (Stx + Ssy) - cc * cc * Sw;
            const double nSyy =  r * r * Sxx - r * cc * (Stx + Ssx) + cc * cc * Sw;
            Ssx = nSsx; Ssy = nSsy; Stx = nStx; Sty = nSty;
            Sxx = nSxx; Sxy = nSxy; Syx = nSyx; Syy = nSyy;
        }

        const double wd  = Sw + 1e-4;
        const double scx = Ssx / wd, scy = Ssy / wd;
        const double tcx = Stx / wd, tcy = Sty / wd;

        const double W00 = (Sxx - tcx * Ssx - scx * Stx + tcx * scx * Sw) / wd;
        const double W01 = (Sxy - tcx * Ssy - scy * Stx + tcx * scy * Sw) / wd;
        const double W10 = (Syx - tcy * Ssx - scx * Sty + tcy * scx * Sw) / wd;
        const double W11 = (Syy - tcy * Ssy - scy * Sty + tcy * scy * Sw) / wd;

        const double det = W00 * W11 - W01 * W10;

        // 2x2 orthogonal polar factor of W (== U2 @ V2^T), and
        // R[2][2] = sign(det) from Kabsch diag(1,1,detU*detV).
        double R00, R01, R10, R11, dsign;
        if (det >= 0.0) {
            const double p = W00 + W11;
            const double q = W10 - W01;
            double r2 = sqrt(p * p + q * q);
            if (r2 > 0.0) {
                R00 = p / r2;  R01 = -q / r2;
                R10 = q / r2;  R11 = p / r2;
            } else {
                R00 = 1.0; R01 = 0.0; R10 = 0.0; R11 = 1.0;
            }
            dsign = 1.0;
        } else {
            const double p = W00 - W11;
            const double q = W01 + W10;
            const double r2 = sqrt(p * p + q * q);  // > 0 when det < 0
            R00 = p / r2;   R01 = q / r2;
            R10 = q / r2;   R11 = -p / r2;
            dsign = -1.0;
        }

        // t_tgt_src_insrc = src_centroid - R^T @ tgt_centroid (z == 0)
        const double tt0 = scx - (R00 * tcx + R10 * tcy);
        const double tt1 = scy - (R01 * tcx + R11 * tcy);
        // t_src_tgt_intgt = -R @ t_tgt_src_insrc
        const double o0 = -(R00 * tt0 + R01 * tt1);
        const double o1 = -(R10 * tt0 + R11 * tt1);

        // Output 0: R^T, row-major [3][3]
        float* oR = out + (size_t)b * 9;
        oR[0] = (float)R00; oR[1] = (float)R10; oR[2] = 0.f;
        oR[3] = (float)R01; oR[4] = (float)R11; oR[5] = 0.f;
        oR[6] = 0.f;        oR[7] = 0.f;        oR[8] = (float)dsign;

        // Output 1: translation [3][1]
        float* oT = out + (size_t)BATCH * 9 + (size_t)b * 3;
        oT[0] = (float)o0; oT[1] = (float)o1; oT[2] = 0.f;
    }
}

extern "C" void kernel_launch(void* const* d_in, const int* in_sizes, int n_in,
                              void* d_out, int out_size, void* d_ws, size_t ws_size,
                              hipStream_t stream) {
    const float* src = (const float*)d_in[0];
    const float* tgt = (const float*)d_in[1];
    const float* wts = (const float*)d_in[2];
    const int*   cvt = (const int*)d_in[3];
    float* out = (float*)d_out;

    svd_align_kernel<<<BATCH, 256, 0, stream>>>(src, tgt, wts, cvt, out);
}